// Round 8
// baseline (594.459 us; speedup 1.0000x reference)
//
#include <hip/hip_runtime.h>
#include <hip/hip_fp16.h>

#define Tt 512

typedef _Float16 f16x8 __attribute__((ext_vector_type(8)));
typedef float    f32x4 __attribute__((ext_vector_type(4)));

// Workspace byte offsets
#define BP16_OFF 0ul                              // fp16 B panel [1280][320]
#define BP16_BYTES (2ul*1280*320)                 // 819,200
#define WHHM_OFF (BP16_OFF + BP16_BYTES)
#define WHHM_BYTES (16ul*2*10*4*5*64)             // 409,600 MFMA W fragments
#define BIAS_OFF (WHHM_OFF + WHHM_BYTES)
#define BIAS_BYTES (4ul*1280)
#define XG_OFF   (4ul*1024*1024)                  // fp16 xg [65536][1280] = 167.8 MB

__device__ __forceinline__ float sig2(float x) {
    return __builtin_amdgcn_rcpf(1.f + __builtin_amdgcn_exp2f(-1.442695041f * x));
}
__device__ __forceinline__ float tanh2(float x) {
    return 2.f * __builtin_amdgcn_rcpf(1.f + __builtin_amdgcn_exp2f(-2.885390082f * x)) - 1.f;
}

// ---------------- Kernel 0: pack weights ----------------
// Bp[n][k] fp16: n = dir*640 + u*4 + q  (gate-adjacent!), k = e (320, pad 0)
// Whhm: uint4 fragment at ((dir*10+w)*20 + q*5 + kk)*64 + l :
//   8 halfs = W_hh[q*150 + (w*16 + (l&15))][kk*32 + (l>>4)*8 + i]  (0 outside)
// bias_p[n] fp32, same n-remap as Bp.
__global__ void pack_weights(const float* __restrict__ Wih_f, const float* __restrict__ Whh_f,
                             const float* __restrict__ b_f,
                             const float* __restrict__ Wih_b, const float* __restrict__ Whh_b,
                             const float* __restrict__ b_b,
                             __half* __restrict__ Bp, uint4* __restrict__ Whhm,
                             float* __restrict__ bias_p) {
    int idx = blockIdx.x * 256 + threadIdx.x;
    const int T1 = 1280 * 320;
    const int T2 = 2 * 10 * 4 * 5 * 64;
    const int T3 = 1280;
    if (idx < T1) {
        int n = idx / 320, k = idx % 320;
        int dir = (n >= 640);
        int j2  = n - dir * 640;
        int u = j2 >> 2, q = j2 & 3;       // gate-adjacent: n = u*4 + q
        const float* W = dir ? Wih_b : Wih_f;
        Bp[idx] = __float2half((u < 150 && k < 300) ? W[(q * 150 + u) * 300 + k] : 0.f);
    } else if ((idx -= T1) < T2) {
        int l  = idx & 63;
        int r  = idx >> 6;
        int kk = r % 5;  r /= 5;
        int q  = r % 4;  r /= 4;
        int w  = r % 10;
        int dir = r / 10;
        int unit  = w * 16 + (l & 15);
        int kbase = kk * 32 + (l >> 4) * 8;
        const float* W = dir ? Whh_b : Whh_f;
        union { __half h[8]; uint4 u4; } pk;
#pragma unroll
        for (int i = 0; i < 8; ++i) {
            int k = kbase + i;
            pk.h[i] = __float2half((unit < 150 && k < 150)
                                   ? W[(q * 150 + unit) * 150 + k] : 0.f);
        }
        Whhm[idx] = pk.u4;
    } else if ((idx -= T2) < T3) {
        int n = idx;
        int dir = (n >= 640);
        int j2  = n - dir * 640;
        int u = j2 >> 2, q = j2 & 3;
        const float* bb = dir ? b_b : b_f;
        bias_p[n] = (u < 150) ? bb[q * 150 + u] : 0.f;
    }
}

// ---------------- Kernel 1: xg GEMM via MFMA (unchanged from R3) ----------------
__global__ __launch_bounds__(256) void gemm_xg(const float* __restrict__ x,
                                               const uint4* __restrict__ Bp,
                                               const float* __restrict__ bias_p,
                                               __half* __restrict__ xg) {
    __shared__ uint4 Bsh[5120];
    const int tid = threadIdx.x;
    const int bid = blockIdx.x;
    const int xcd = bid & 7, li = bid >> 3;
    const int mb  = xcd * 64 + li / 10;
    const int nb  = li % 10;

    {
        const uint4* src = Bp + (size_t)nb * 128 * 40;
        for (int c = tid; c < 5120; c += 256) {
            int n = c / 40, ch = c - n * 40;
            Bsh[n * 40 + (ch ^ (n & 7))] = src[c];
        }
    }

    const int w  = tid >> 6;
    const int l  = tid & 63;
    const int wr = w >> 1, wc = w & 1;
    const int lr = l & 15, kg = l >> 4;

    f32x4 acc[4][4];
#pragma unroll
    for (int mf = 0; mf < 4; ++mf)
#pragma unroll
        for (int nf = 0; nf < 4; ++nf) acc[mf][nf] = (f32x4)0.f;

    const float* arow0 = x + (size_t)(mb * 128 + wr * 64 + lr) * 300 + kg * 8;
    const float* arow1 = arow0 + 16 * 300;
    const float* arow2 = arow0 + 32 * 300;
    const float* arow3 = arow0 + 48 * 300;
    const float4 fz4 = make_float4(0.f, 0.f, 0.f, 0.f);

    float cur[2][4][8];
#define LOADA(BUF, KB, GUARD)                                                   \
    {                                                                           \
        const float* ap_[4] = {arow0, arow1, arow2, arow3};                     \
        _Pragma("unroll")                                                       \
        for (int mf = 0; mf < 4; ++mf) {                                        \
            const float* ap = ap_[mf] + (KB) * 32;                              \
            *(float4*)&cur[BUF][mf][0] =                                        \
                (!(GUARD) || (KB) * 32 + kg * 8 < 300) ? *(const float4*)ap : fz4; \
            *(float4*)&cur[BUF][mf][4] =                                        \
                (!(GUARD) || (KB) * 32 + kg * 8 + 4 < 300) ? *(const float4*)(ap + 4) : fz4; \
        }                                                                       \
    }

    __syncthreads();

    LOADA(0, 0, false);
#pragma unroll
    for (int kb = 0; kb < 10; ++kb) {
        const int pb = kb & 1, nx = pb ^ 1;
        if (kb < 8)       { LOADA(nx, kb + 1, false); }
        else if (kb == 8) { LOADA(nx, 9, true); }

        uint4 bf[4];
#pragma unroll
        for (int nf = 0; nf < 4; ++nf)
            bf[nf] = Bsh[(wc * 64 + nf * 16 + lr) * 40 + ((kb * 4 + kg) ^ (lr & 7))];

        f16x8 af[4];
#pragma unroll
        for (int mf = 0; mf < 4; ++mf)
#pragma unroll
            for (int i = 0; i < 8; ++i) af[mf][i] = (_Float16)cur[pb][mf][i];

#pragma unroll
        for (int mf = 0; mf < 4; ++mf)
#pragma unroll
            for (int nf = 0; nf < 4; ++nf)
                acc[mf][nf] = __builtin_amdgcn_mfma_f32_16x16x32_f16(
                    __builtin_bit_cast(f16x8, bf[nf]), af[mf], acc[mf][nf], 0, 0, 0);
    }

    const int mrow = mb * 128 + wr * 64;
    const int ncol = nb * 128 + wc * 64;
#pragma unroll
    for (int mf = 0; mf < 4; ++mf) {
        int m_g = mrow + mf * 16 + lr;
        __half* orow = xg + (size_t)m_g * 1280;
#pragma unroll
        for (int nf = 0; nf < 4; ++nf) {
            int n_g = ncol + nf * 16 + kg * 4;
            float4 bv = *(const float4*)(bias_p + n_g);
            f32x4 v = acc[mf][nf];
            union { __half h[4]; uint2 u; } pk;
            pk.h[0] = __float2half(v[0] + bv.x);
            pk.h[1] = __float2half(v[1] + bv.y);
            pk.h[2] = __float2half(v[2] + bv.z);
            pk.h[3] = __float2half(v[3] + bv.w);
            *(uint2*)(orow + n_g) = pk.u;
        }
    }
#undef LOADA
}

// ---------------- Kernel 2: MFMA recurrence + pooling ----------------
// 64 blocks = (32 sample-groups x 2 dir) x 640 threads (10 waves).
// h stored in LDS as packed A-fragments [kk][hik][s][8 halfs] (256 B/chunk):
// ds_read_b128 conflict-free (16 contiguous addrs x 4-lane broadcast).
// xg gate-adjacent: one 8-B load gives all 4 gate biases of the lane's unit.
__global__ __launch_bounds__(640, 1) void lstm_rec(const uint4* __restrict__ Whhm,
                                                   const __half* __restrict__ xg,
                                                   const int* __restrict__ lens,
                                                   float* __restrict__ out) {
    __shared__ __align__(16) unsigned hbuf[640];   // 2 x 1280 B fragment buffers
    const int tid = threadIdx.x, l = tid & 63, w = tid >> 6;
    const int dir = blockIdx.x & 1, sg = blockIdx.x >> 1;
    const int lr = l & 15, hi = l >> 4;
    const int unit = w * 16 + lr;
    const int b = sg * 4 + hi;

    hbuf[tid < 640 ? tid : 0] = 0u;

    // W fragments consumed directly by MFMA
    uint4 wf[20];
    const uint4* wsrc = Whhm + (size_t)(dir * 10 + w) * 20 * 64 + l;
#pragma unroll
    for (int f = 0; f < 20; ++f) wf[f] = wsrc[(size_t)f * 64];

    float c_s = 0.f, hsum = 0.f, hlast = 0.f;
    const int Lv = lens[b];
    const int mark = dir ? (Tt - Lv) : (Lv - 1);

    // loop-invariant LDS byte offsets
    const int rdoff = (l >> 4) * 64 + ((l >> 2) & 3) * 16;  // + kk*256 immediate
    const int wroff = (w >> 1) * 256 + ((w & 1) * 2 + (lr >> 3)) * 64 + hi * 16 + (lr & 7) * 2;

    const __half* xb = xg + (size_t)b * 512 * 1280 + dir * 640 + unit * 4;

#define T_OF(S) ((dir) ? (511 - ((S) < Tt ? (S) : Tt - 1)) : ((S) < Tt ? (S) : Tt - 1))

    uint2 xq0 = *(const uint2*)(xb + (size_t)T_OF(0) * 1280);
    uint2 xq1 = *(const uint2*)(xb + (size_t)T_OF(1) * 1280);

    __syncthreads();

    for (int step = 0; step < Tt; ++step) {
        const int P = step & 1;
        uint2 xq2 = *(const uint2*)(xb + (size_t)T_OF(step + 2) * 1280);  // prefetch

        uint4 af[5];
        const char* rbase = (const char*)hbuf + (P * 1280 + rdoff);
#pragma unroll
        for (int kk = 0; kk < 5; ++kk)
            af[kk] = *(const uint4*)(rbase + kk * 256);

        __half2 x01 = __builtin_bit_cast(__half2, xq0.x);
        __half2 x23 = __builtin_bit_cast(__half2, xq0.y);
        f32x4 a0 = (f32x4)0.f, a1 = (f32x4)0.f, a2 = (f32x4)0.f, a3 = (f32x4)0.f;
        a0[0] = __half2float(x01.x);
        a1[0] = __half2float(x01.y);
        a2[0] = __half2float(x23.x);
        a3[0] = __half2float(x23.y);

#pragma unroll
        for (int kk = 0; kk < 5; ++kk) {
            f16x8 hv = __builtin_bit_cast(f16x8, af[kk]);
            a0 = __builtin_amdgcn_mfma_f32_16x16x32_f16(
                hv, __builtin_bit_cast(f16x8, wf[0 * 5 + kk]), a0, 0, 0, 0);
            a1 = __builtin_amdgcn_mfma_f32_16x16x32_f16(
                hv, __builtin_bit_cast(f16x8, wf[1 * 5 + kk]), a1, 0, 0, 0);
            a2 = __builtin_amdgcn_mfma_f32_16x16x32_f16(
                hv, __builtin_bit_cast(f16x8, wf[2 * 5 + kk]), a2, 0, 0, 0);
            a3 = __builtin_amdgcn_mfma_f32_16x16x32_f16(
                hv, __builtin_bit_cast(f16x8, wf[3 * 5 + kk]), a3, 0, 0, 0);
        }

        float i_ = sig2(a0[0]);
        float f_ = sig2(a1[0]);
        float g_ = tanh2(a2[0]);
        float o_ = sig2(a3[0]);
        c_s = f_ * c_s + i_ * g_;
        float h = o_ * tanh2(c_s);
        bool in = dir ? (step >= mark) : (step < Lv);
        if (in) hsum += h;
        if (step == mark) hlast = h;
        *(__half*)((char*)hbuf + ((P ^ 1) * 1280 + wroff)) = __float2half(h);

        xq0 = xq1; xq1 = xq2;
        __syncthreads();
    }
#undef T_OF

    if (unit < 150) {
        out[b * 600 + dir * 150 + unit]       = tanh2(hsum / (float)Lv);
        out[b * 600 + 300 + dir * 150 + unit] = tanh2(hlast);
    }
}

// ---------------- launch ----------------
extern "C" void kernel_launch(void* const* d_in, const int* in_sizes, int n_in,
                              void* d_out, int out_size, void* d_ws, size_t ws_size,
                              hipStream_t stream) {
    const float* x     = (const float*)d_in[0];
    const int*   lens  = (const int*)d_in[1];
    const float* Wih_f = (const float*)d_in[2];
    const float* Whh_f = (const float*)d_in[3];
    const float* b_f   = (const float*)d_in[4];
    const float* Wih_b = (const float*)d_in[5];
    const float* Whh_b = (const float*)d_in[6];
    const float* b_b   = (const float*)d_in[7];
    float* out = (float*)d_out;
    char*  ws  = (char*)d_ws;

    __half* Bp     = (__half*)(ws + BP16_OFF);
    uint4*  Whhm   = (uint4*)(ws + WHHM_OFF);
    float*  bias_p = (float*)(ws + BIAS_OFF);
    __half* xg     = (__half*)(ws + XG_OFF);

    {
        int total = 1280 * 320 + 2 * 10 * 4 * 5 * 64 + 1280;
        int blocks = (total + 255) / 256;
        pack_weights<<<blocks, 256, 0, stream>>>(Wih_f, Whh_f, b_f, Wih_b, Whh_b, b_b,
                                                 Bp, Whhm, bias_p);
    }
    {
        gemm_xg<<<5120, 256, 0, stream>>>(x, (const uint4*)Bp, bias_p, xg);
    }
    {
        lstm_rec<<<64, 640, 0, stream>>>(Whhm, xg, lens, out);
    }
}

// Round 9
// 583.353 us; speedup vs baseline: 1.0190x; 1.0190x over previous
//
#include <hip/hip_runtime.h>
#include <hip/hip_fp16.h>

#define Tt 512

typedef _Float16 f16x8 __attribute__((ext_vector_type(8)));
typedef float    f32x4 __attribute__((ext_vector_type(4)));

// Workspace byte offsets
#define BP16_OFF 0ul                              // fp16 B panel [1280][320]
#define BP16_BYTES (2ul*1280*320)                 // 819,200
#define WHHM_OFF (BP16_OFF + BP16_BYTES)
#define WHHM_BYTES (16ul*2*10*4*5*64)             // 409,600 MFMA W fragments
#define BIAS_OFF (WHHM_OFF + WHHM_BYTES)
#define BIAS_BYTES (4ul*1280)
#define XG_OFF   (4ul*1024*1024)                  // fp16 xg [65536][1280] = 167.8 MB

__device__ __forceinline__ float sig2(float x) {
    return __builtin_amdgcn_rcpf(1.f + __builtin_amdgcn_exp2f(-1.442695041f * x));
}
__device__ __forceinline__ float tanh2(float x) {
    return 2.f * __builtin_amdgcn_rcpf(1.f + __builtin_amdgcn_exp2f(-2.885390082f * x)) - 1.f;
}

// ---------------- Kernel 0: pack weights (unchanged from R8) ----------------
__global__ void pack_weights(const float* __restrict__ Wih_f, const float* __restrict__ Whh_f,
                             const float* __restrict__ b_f,
                             const float* __restrict__ Wih_b, const float* __restrict__ Whh_b,
                             const float* __restrict__ b_b,
                             __half* __restrict__ Bp, uint4* __restrict__ Whhm,
                             float* __restrict__ bias_p) {
    int idx = blockIdx.x * 256 + threadIdx.x;
    const int T1 = 1280 * 320;
    const int T2 = 2 * 10 * 4 * 5 * 64;
    const int T3 = 1280;
    if (idx < T1) {
        int n = idx / 320, k = idx % 320;
        int dir = (n >= 640);
        int j2  = n - dir * 640;
        int u = j2 >> 2, q = j2 & 3;       // gate-adjacent: n = u*4 + q
        const float* W = dir ? Wih_b : Wih_f;
        Bp[idx] = __float2half((u < 150 && k < 300) ? W[(q * 150 + u) * 300 + k] : 0.f);
    } else if ((idx -= T1) < T2) {
        int l  = idx & 63;
        int r  = idx >> 6;
        int kk = r % 5;  r /= 5;
        int q  = r % 4;  r /= 4;
        int w  = r % 10;
        int dir = r / 10;
        int unit  = w * 16 + (l & 15);
        int kbase = kk * 32 + (l >> 4) * 8;
        const float* W = dir ? Whh_b : Whh_f;
        union { __half h[8]; uint4 u4; } pk;
#pragma unroll
        for (int i = 0; i < 8; ++i) {
            int k = kbase + i;
            pk.h[i] = __float2half((unit < 150 && k < 150)
                                   ? W[(q * 150 + unit) * 150 + k] : 0.f);
        }
        Whhm[idx] = pk.u4;
    } else if ((idx -= T2) < T3) {
        int n = idx;
        int dir = (n >= 640);
        int j2  = n - dir * 640;
        int u = j2 >> 2, q = j2 & 3;
        const float* bb = dir ? b_b : b_f;
        bias_p[n] = (u < 150) ? bb[q * 150 + u] : 0.f;
    }
}

// ---------------- Kernel 1: xg GEMM via MFMA ----------------
// BM=256, BN=128, 512 threads = 8 waves (4x2) -> 2 waves/SIMD (latency hiding).
// Full-K B panel (80 KB, XOR-swizzled) staged once; A streamed fp32->fp16,
// double-buffered in registers. No K-loop barriers.
__global__ __launch_bounds__(512) void gemm_xg(const float* __restrict__ x,
                                               const uint4* __restrict__ Bp,
                                               const float* __restrict__ bias_p,
                                               __half* __restrict__ xg) {
    __shared__ uint4 Bsh[5120];
    const int tid = threadIdx.x;
    const int bid = blockIdx.x;
    // XCD-chunked: 2560 = 8 * 320; 32 mb-tiles + their 10 nb each per XCD
    const int xcd = bid & 7, li = bid >> 3;
    const int mb  = xcd * 32 + li / 10;
    const int nb  = li % 10;

    {   // stage B panel (one-time)
        const uint4* src = Bp + (size_t)nb * 128 * 40;
        for (int c = tid; c < 5120; c += 512) {
            int n = c / 40, ch = c - n * 40;
            Bsh[n * 40 + (ch ^ (n & 7))] = src[c];
        }
    }

    const int w  = tid >> 6;
    const int l  = tid & 63;
    const int wr = w >> 1, wc = w & 1;    // 4 M-waves x 2 N-waves
    const int lr = l & 15, kg = l >> 4;

    f32x4 acc[4][4];
#pragma unroll
    for (int mf = 0; mf < 4; ++mf)
#pragma unroll
        for (int nf = 0; nf < 4; ++nf) acc[mf][nf] = (f32x4)0.f;

    const float* arow0 = x + (size_t)(mb * 256 + wr * 64 + lr) * 300 + kg * 8;
    const float* arow1 = arow0 + 16 * 300;
    const float* arow2 = arow0 + 32 * 300;
    const float* arow3 = arow0 + 48 * 300;
    const float4 fz4 = make_float4(0.f, 0.f, 0.f, 0.f);

    float cur[2][4][8];
#define LOADA(BUF, KB, GUARD)                                                   \
    {                                                                           \
        const float* ap_[4] = {arow0, arow1, arow2, arow3};                     \
        _Pragma("unroll")                                                       \
        for (int mf = 0; mf < 4; ++mf) {                                        \
            const float* ap = ap_[mf] + (KB) * 32;                              \
            *(float4*)&cur[BUF][mf][0] =                                        \
                (!(GUARD) || (KB) * 32 + kg * 8 < 300) ? *(const float4*)ap : fz4; \
            *(float4*)&cur[BUF][mf][4] =                                        \
                (!(GUARD) || (KB) * 32 + kg * 8 + 4 < 300) ? *(const float4*)(ap + 4) : fz4; \
        }                                                                       \
    }

    __syncthreads();   // B panel ready

    LOADA(0, 0, false);
#pragma unroll
    for (int kb = 0; kb < 10; ++kb) {
        const int pb = kb & 1, nx = pb ^ 1;
        if (kb < 8)       { LOADA(nx, kb + 1, false); }
        else if (kb == 8) { LOADA(nx, 9, true); }

        uint4 bf[4];
#pragma unroll
        for (int nf = 0; nf < 4; ++nf)
            bf[nf] = Bsh[(wc * 64 + nf * 16 + lr) * 40 + ((kb * 4 + kg) ^ (lr & 7))];

        f16x8 af[4];
#pragma unroll
        for (int mf = 0; mf < 4; ++mf)
#pragma unroll
            for (int i = 0; i < 8; ++i) af[mf][i] = (_Float16)cur[pb][mf][i];

#pragma unroll
        for (int mf = 0; mf < 4; ++mf)
#pragma unroll
            for (int nf = 0; nf < 4; ++nf)
                acc[mf][nf] = __builtin_amdgcn_mfma_f32_16x16x32_f16(
                    __builtin_bit_cast(f16x8, bf[nf]), af[mf], acc[mf][nf], 0, 0, 0);
    }

    // Epilogue: D[n][m] layout -> lane holds 4 consecutive n at fixed m.
    const int mrow = mb * 256 + wr * 64;
    const int ncol = nb * 128 + wc * 64;
#pragma unroll
    for (int mf = 0; mf < 4; ++mf) {
        int m_g = mrow + mf * 16 + lr;
        __half* orow = xg + (size_t)m_g * 1280;
#pragma unroll
        for (int nf = 0; nf < 4; ++nf) {
            int n_g = ncol + nf * 16 + kg * 4;
            float4 bv = *(const float4*)(bias_p + n_g);
            f32x4 v = acc[mf][nf];
            union { __half h[4]; uint2 u; } pk;
            pk.h[0] = __float2half(v[0] + bv.x);
            pk.h[1] = __float2half(v[1] + bv.y);
            pk.h[2] = __float2half(v[2] + bv.z);
            pk.h[3] = __float2half(v[3] + bv.w);
            *(uint2*)(orow + n_g) = pk.u;
        }
    }
#undef LOADA
}

// ---------------- Kernel 2: MFMA recurrence + pooling (unchanged from R8) ----------------
__global__ __launch_bounds__(640, 1) void lstm_rec(const uint4* __restrict__ Whhm,
                                                   const __half* __restrict__ xg,
                                                   const int* __restrict__ lens,
                                                   float* __restrict__ out) {
    __shared__ __align__(16) unsigned hbuf[640];   // 2 x 1280 B fragment buffers
    const int tid = threadIdx.x, l = tid & 63, w = tid >> 6;
    const int dir = blockIdx.x & 1, sg = blockIdx.x >> 1;
    const int lr = l & 15, hi = l >> 4;
    const int unit = w * 16 + lr;
    const int b = sg * 4 + hi;

    hbuf[tid < 640 ? tid : 0] = 0u;

    // W fragments consumed directly by MFMA
    uint4 wf[20];
    const uint4* wsrc = Whhm + (size_t)(dir * 10 + w) * 20 * 64 + l;
#pragma unroll
    for (int f = 0; f < 20; ++f) wf[f] = wsrc[(size_t)f * 64];

    float c_s = 0.f, hsum = 0.f, hlast = 0.f;
    const int Lv = lens[b];
    const int mark = dir ? (Tt - Lv) : (Lv - 1);

    // loop-invariant LDS byte offsets
    const int rdoff = (l >> 4) * 64 + ((l >> 2) & 3) * 16;  // + kk*256 immediate
    const int wroff = (w >> 1) * 256 + ((w & 1) * 2 + (lr >> 3)) * 64 + hi * 16 + (lr & 7) * 2;

    const __half* xb = xg + (size_t)b * 512 * 1280 + dir * 640 + unit * 4;

#define T_OF(S) ((dir) ? (511 - ((S) < Tt ? (S) : Tt - 1)) : ((S) < Tt ? (S) : Tt - 1))

    uint2 xq0 = *(const uint2*)(xb + (size_t)T_OF(0) * 1280);
    uint2 xq1 = *(const uint2*)(xb + (size_t)T_OF(1) * 1280);

    __syncthreads();

    for (int step = 0; step < Tt; ++step) {
        const int P = step & 1;
        uint2 xq2 = *(const uint2*)(xb + (size_t)T_OF(step + 2) * 1280);  // prefetch

        uint4 af[5];
        const char* rbase = (const char*)hbuf + (P * 1280 + rdoff);
#pragma unroll
        for (int kk = 0; kk < 5; ++kk)
            af[kk] = *(const uint4*)(rbase + kk * 256);

        __half2 x01 = __builtin_bit_cast(__half2, xq0.x);
        __half2 x23 = __builtin_bit_cast(__half2, xq0.y);
        f32x4 a0 = (f32x4)0.f, a1 = (f32x4)0.f, a2 = (f32x4)0.f, a3 = (f32x4)0.f;
        a0[0] = __half2float(x01.x);
        a1[0] = __half2float(x01.y);
        a2[0] = __half2float(x23.x);
        a3[0] = __half2float(x23.y);

#pragma unroll
        for (int kk = 0; kk < 5; ++kk) {
            f16x8 hv = __builtin_bit_cast(f16x8, af[kk]);
            a0 = __builtin_amdgcn_mfma_f32_16x16x32_f16(
                hv, __builtin_bit_cast(f16x8, wf[0 * 5 + kk]), a0, 0, 0, 0);
            a1 = __builtin_amdgcn_mfma_f32_16x16x32_f16(
                hv, __builtin_bit_cast(f16x8, wf[1 * 5 + kk]), a1, 0, 0, 0);
            a2 = __builtin_amdgcn_mfma_f32_16x16x32_f16(
                hv, __builtin_bit_cast(f16x8, wf[2 * 5 + kk]), a2, 0, 0, 0);
            a3 = __builtin_amdgcn_mfma_f32_16x16x32_f16(
                hv, __builtin_bit_cast(f16x8, wf[3 * 5 + kk]), a3, 0, 0, 0);
        }

        float i_ = sig2(a0[0]);
        float f_ = sig2(a1[0]);
        float g_ = tanh2(a2[0]);
        float o_ = sig2(a3[0]);
        c_s = f_ * c_s + i_ * g_;
        float h = o_ * tanh2(c_s);
        bool in = dir ? (step >= mark) : (step < Lv);
        if (in) hsum += h;
        if (step == mark) hlast = h;
        *(__half*)((char*)hbuf + ((P ^ 1) * 1280 + wroff)) = __float2half(h);

        xq0 = xq1; xq1 = xq2;
        __syncthreads();
    }
#undef T_OF

    if (unit < 150) {
        out[b * 600 + dir * 150 + unit]       = tanh2(hsum / (float)Lv);
        out[b * 600 + 300 + dir * 150 + unit] = tanh2(hlast);
    }
}

// ---------------- launch ----------------
extern "C" void kernel_launch(void* const* d_in, const int* in_sizes, int n_in,
                              void* d_out, int out_size, void* d_ws, size_t ws_size,
                              hipStream_t stream) {
    const float* x     = (const float*)d_in[0];
    const int*   lens  = (const int*)d_in[1];
    const float* Wih_f = (const float*)d_in[2];
    const float* Whh_f = (const float*)d_in[3];
    const float* b_f   = (const float*)d_in[4];
    const float* Wih_b = (const float*)d_in[5];
    const float* Whh_b = (const float*)d_in[6];
    const float* b_b   = (const float*)d_in[7];
    float* out = (float*)d_out;
    char*  ws  = (char*)d_ws;

    __half* Bp     = (__half*)(ws + BP16_OFF);
    uint4*  Whhm   = (uint4*)(ws + WHHM_OFF);
    float*  bias_p = (float*)(ws + BIAS_OFF);
    __half* xg     = (__half*)(ws + XG_OFF);

    {
        int total = 1280 * 320 + 2 * 10 * 4 * 5 * 64 + 1280;
        int blocks = (total + 255) / 256;
        pack_weights<<<blocks, 256, 0, stream>>>(Wih_f, Whh_f, b_f, Wih_b, Whh_b, b_b,
                                                 Bp, Whhm, bias_p);
    }
    {
        gemm_xg<<<2560, 512, 0, stream>>>(x, (const uint4*)Bp, bias_p, xg);
    }
    {
        lstm_rec<<<64, 640, 0, stream>>>(Whhm, xg, lens, out);
    }
}